// Round 1
// baseline (317.827 us; speedup 1.0000x reference)
//
#include <hip/hip_runtime.h>

#define LL 4
#define BB 32
#define SS 512
#define FF 768
#define NW 257        // W_MAX + 1
#define F4 192        // FF / 4

__device__ __forceinline__ void f4add(float4& a, const float4& b) {
    a.x += b.x; a.y += b.y; a.z += b.z; a.w += b.w;
}

// ---- counts: one block per b, 512 threads, LDS histogram ----
__global__ void k_counts(const int* __restrict__ wid, int* __restrict__ counts) {
    __shared__ int lc[NW];
    int b = blockIdx.x;
    for (int i = threadIdx.x; i < NW; i += blockDim.x) lc[i] = 0;
    __syncthreads();
    atomicAdd(&lc[wid[b * SS + threadIdx.x]], 1);
    __syncthreads();
    for (int i = threadIdx.x; i < NW; i += blockDim.x) counts[b * NW + i] = lc[i];
}

// ---- main: layer-mix + run-compressed segment-sum atomics + sentence partials ----
// grid: BB * 8 * 3 blocks of 256 threads
// block -> (b, sg in 0..7 [64 s each], fc in 0..2 [64 float4 each])
// thread t: lane = t&63 -> f4 = fc*64+lane ; swave = t>>6 -> s in [s0, s0+16)
__global__ void k_main(const float* __restrict__ hs, const float* __restrict__ lw,
                       const float* __restrict__ gm, const int* __restrict__ wid,
                       float* __restrict__ out, float* __restrict__ partials) {
    int bid = blockIdx.x;
    int fc = bid % 3;
    int sg = (bid / 3) & 7;
    int b  = bid / 24;
    int t = threadIdx.x;
    int lane = t & 63;
    int swave = t >> 6;
    int f4 = fc * 64 + lane;
    int s0 = sg * 64 + swave * 16;

    // softmax(layer_weights) * gamma  (tiny, all-lane broadcast loads)
    float w0 = lw[0], w1 = lw[1], w2 = lw[2], w3 = lw[3];
    float mx = fmaxf(fmaxf(w0, w1), fmaxf(w2, w3));
    float e0 = __expf(w0 - mx), e1 = __expf(w1 - mx);
    float e2 = __expf(w2 - mx), e3 = __expf(w3 - mx);
    float g = gm[0] / (e0 + e1 + e2 + e3);
    float c0 = e0 * g, c1 = e1 * g, c2 = e2 * g, c3 = e3 * g;

    const float4* h4 = (const float4*)hs;
    const int ls = BB * SS * F4;                  // layer stride in float4s
    int base = (b * SS + s0) * F4 + f4;
    const int* wrow = wid + b * SS + s0;

    float4 sent = {0.f, 0.f, 0.f, 0.f};
    float4 run  = {0.f, 0.f, 0.f, 0.f};
    int prev = wrow[0];

    #pragma unroll
    for (int k = 0; k < 16; k++) {
        int w = wrow[k];                          // wave-uniform (all lanes same s)
        int idx = base + k * F4;
        float4 a  = h4[idx];
        float4 bv = h4[idx + ls];
        float4 cv = h4[idx + 2 * ls];
        float4 dv = h4[idx + 3 * ls];
        float4 v;
        v.x = c0 * a.x + c1 * bv.x + c2 * cv.x + c3 * dv.x;
        v.y = c0 * a.y + c1 * bv.y + c2 * cv.y + c3 * dv.y;
        v.z = c0 * a.z + c1 * bv.z + c2 * cv.z + c3 * dv.z;
        v.w = c0 * a.w + c1 * bv.w + c2 * cv.w + c3 * dv.w;
        f4add(sent, v);
        if (w != prev) {                          // wave-uniform branch
            float* p = out + (prev + b * NW) * FF + f4 * 4;
            atomicAdd(p + 0, run.x); atomicAdd(p + 1, run.y);
            atomicAdd(p + 2, run.z); atomicAdd(p + 3, run.w);
            run = v; prev = w;
        } else {
            f4add(run, v);
        }
    }
    {
        float* p = out + (prev + b * NW) * FF + f4 * 4;
        atomicAdd(p + 0, run.x); atomicAdd(p + 1, run.y);
        atomicAdd(p + 2, run.z); atomicAdd(p + 3, run.w);
    }

    // sentence partial: reduce the 4 s-waves, one non-atomic store per (b,sg,f4)
    __shared__ float4 sm[256];
    sm[t] = sent;
    __syncthreads();
    if (t < 64) {
        float4 tot = sm[t];
        f4add(tot, sm[t + 64]);
        f4add(tot, sm[t + 128]);
        f4add(tot, sm[t + 192]);
        ((float4*)partials)[(b * 8 + sg) * F4 + f4] = tot;   // f4 == fc*64 + t
    }
}

// ---- divide sums by counts (skip w==0; slot 0 written by k_sent) ----
__global__ void k_means(float* __restrict__ out, const int* __restrict__ counts) {
    int t = blockIdx.x * 256 + threadIdx.x;
    if (t >= BB * NW * F4) return;
    int f4 = t % F4;
    int r = t / F4;
    int w = r % NW;
    int b = r / NW;
    if (w == 0) return;
    int c = counts[b * NW + w];
    float inv = 1.0f / (float)(c > 1 ? c : 1);
    float4* p = (float4*)out + (b * NW + w) * F4 + f4;
    float4 v = *p;
    v.x *= inv; v.y *= inv; v.z *= inv; v.w *= inv;
    *p = v;
}

// ---- sentence mean into slot 0 ----
__global__ void k_sent(const float* __restrict__ partials, float* __restrict__ out) {
    int t = blockIdx.x * 256 + threadIdx.x;
    if (t >= BB * F4) return;
    int f4 = t % F4;
    int b = t / F4;
    const float4* p4 = (const float4*)partials;
    float4 tot = {0.f, 0.f, 0.f, 0.f};
    #pragma unroll
    for (int g = 0; g < 8; g++) f4add(tot, p4[(b * 8 + g) * F4 + f4]);
    const float s = 1.0f / (float)SS;
    tot.x *= s; tot.y *= s; tot.z *= s; tot.w *= s;
    ((float4*)out)[(size_t)b * NW * F4 + f4] = tot;
}

extern "C" void kernel_launch(void* const* d_in, const int* in_sizes, int n_in,
                              void* d_out, int out_size, void* d_ws, size_t ws_size,
                              hipStream_t stream) {
    const float* hs  = (const float*)d_in[0];   // (L,B,S,F) f32
    const float* lw  = (const float*)d_in[1];   // (L,)
    const float* gm  = (const float*)d_in[2];   // (1,)
    const int*   wid = (const int*)d_in[3];     // (B,S) int32, sorted per row
    float* out = (float*)d_out;                 // (B, 257, F) f32

    int*   counts   = (int*)d_ws;                                   // BB*NW ints
    float* partials = (float*)((char*)d_ws + 33024);                // BB*8*FF floats

    hipMemsetAsync(d_out, 0, (size_t)out_size * sizeof(float), stream);
    k_counts<<<BB, 512, 0, stream>>>(wid, counts);
    k_main<<<BB * 24, 256, 0, stream>>>(hs, lw, gm, wid, out, partials);
    int nm = BB * NW * F4;
    k_means<<<(nm + 255) / 256, 256, 0, stream>>>(out, counts);
    k_sent<<<(BB * F4 + 255) / 256, 256, 0, stream>>>(partials, out);
}

// Round 2
// 305.130 us; speedup vs baseline: 1.0416x; 1.0416x over previous
//
#include <hip/hip_runtime.h>

#define LL 4
#define BB 32
#define SS 512
#define FF 768
#define NW 257        // W_MAX + 1
#define F4 192        // FF / 4

__device__ __forceinline__ void f4add(float4& a, const float4& b) {
    a.x += b.x; a.y += b.y; a.z += b.z; a.w += b.w;
}

// ---- counts: one block per b, 512 threads, LDS histogram ----
__global__ void k_counts(const int* __restrict__ wid, int* __restrict__ counts) {
    __shared__ int lc[NW];
    int b = blockIdx.x;
    for (int i = threadIdx.x; i < NW; i += blockDim.x) lc[i] = 0;
    __syncthreads();
    atomicAdd(&lc[wid[b * SS + threadIdx.x]], 1);
    __syncthreads();
    for (int i = threadIdx.x; i < NW; i += blockDim.x) counts[b * NW + i] = lc[i];
}

// ---- main: layer-mix + run-compressed segment-sum + sentence partials ----
// grid: BB * 8 * 3 blocks of 256 threads
// block -> (b, sg in 0..7 [64 s each], fc in 0..2 [64 float4 each])
// thread t: lane = t&63 -> f4 = fc*64+lane ; swave = t>>6 -> s in [s0, s0+16)
//
// Runs fully inside a thread's 16-s range have exactly ONE writer -> plain
// coalesced float4 store of the sum. Only runs shared across a thread
// boundary (wid equal across the edge) are flushed with atomicAdd.
__global__ void k_main(const float* __restrict__ hs, const float* __restrict__ lw,
                       const float* __restrict__ gm, const int* __restrict__ wid,
                       float* __restrict__ out, float* __restrict__ partials) {
    int bid = blockIdx.x;
    int fc = bid % 3;
    int sg = (bid / 3) & 7;
    int b  = bid / 24;
    int t = threadIdx.x;
    int lane = t & 63;
    int swave = t >> 6;
    int f4 = fc * 64 + lane;
    int s0 = sg * 64 + swave * 16;

    // softmax(layer_weights) * gamma  (tiny, all-lane broadcast loads)
    float w0 = lw[0], w1 = lw[1], w2 = lw[2], w3 = lw[3];
    float mx = fmaxf(fmaxf(w0, w1), fmaxf(w2, w3));
    float e0 = __expf(w0 - mx), e1 = __expf(w1 - mx);
    float e2 = __expf(w2 - mx), e3 = __expf(w3 - mx);
    float g = gm[0] / (e0 + e1 + e2 + e3);
    float c0 = e0 * g, c1 = e1 * g, c2 = e2 * g, c3 = e3 * g;

    const float4* h4 = (const float4*)hs;
    const int ls = BB * SS * F4;                  // layer stride in float4s
    int base = (b * SS + s0) * F4 + f4;
    const int* wrow = wid + b * SS + s0;

    int prev = wrow[0];
    // shared-across-boundary flags (wave-uniform)
    bool sharedL = (s0 > 0) && (wrow[-1] == prev);
    bool sharedR = (s0 + 16 < SS) && (wrow[16] == wrow[15]);

    float4 sent = {0.f, 0.f, 0.f, 0.f};
    float4 run  = {0.f, 0.f, 0.f, 0.f};
    bool first = true;

    #pragma unroll
    for (int k = 0; k < 16; k++) {
        int w = wrow[k];                          // wave-uniform (all lanes same s)
        int idx = base + k * F4;
        float4 a  = h4[idx];
        float4 bv = h4[idx + ls];
        float4 cv = h4[idx + 2 * ls];
        float4 dv = h4[idx + 3 * ls];
        float4 v;
        v.x = c0 * a.x + c1 * bv.x + c2 * cv.x + c3 * dv.x;
        v.y = c0 * a.y + c1 * bv.y + c2 * cv.y + c3 * dv.y;
        v.z = c0 * a.z + c1 * bv.z + c2 * cv.z + c3 * dv.z;
        v.w = c0 * a.w + c1 * bv.w + c2 * cv.w + c3 * dv.w;
        f4add(sent, v);
        if (w != prev) {                          // wave-uniform branch
            float* p = out + (prev + b * NW) * FF + f4 * 4;
            if (first && sharedL) {
                atomicAdd(p + 0, run.x); atomicAdd(p + 1, run.y);
                atomicAdd(p + 2, run.z); atomicAdd(p + 3, run.w);
            } else {
                *(float4*)p = run;                // exclusive run: plain store
            }
            first = false;
            run = v; prev = w;
        } else {
            f4add(run, v);
        }
    }
    {   // final run: shared with right neighbor (or left, if it spans the range)
        float* p = out + (prev + b * NW) * FF + f4 * 4;
        if ((first && sharedL) || sharedR) {
            atomicAdd(p + 0, run.x); atomicAdd(p + 1, run.y);
            atomicAdd(p + 2, run.z); atomicAdd(p + 3, run.w);
        } else {
            *(float4*)p = run;
        }
    }

    // sentence partial: reduce the 4 s-waves, one non-atomic store per (b,sg,f4)
    __shared__ float4 sm[256];
    sm[t] = sent;
    __syncthreads();
    if (t < 64) {
        float4 tot = sm[t];
        f4add(tot, sm[t + 64]);
        f4add(tot, sm[t + 128]);
        f4add(tot, sm[t + 192]);
        ((float4*)partials)[(b * 8 + sg) * F4 + f4] = tot;   // f4 == fc*64 + t
    }
}

// ---- divide sums by counts (skip w==0; slot 0 written by k_sent) ----
__global__ void k_means(float* __restrict__ out, const int* __restrict__ counts) {
    int t = blockIdx.x * 256 + threadIdx.x;
    if (t >= BB * NW * F4) return;
    int f4 = t % F4;
    int r = t / F4;
    int w = r % NW;
    int b = r / NW;
    if (w == 0) return;
    int c = counts[b * NW + w];
    float inv = 1.0f / (float)(c > 1 ? c : 1);
    float4* p = (float4*)out + (b * NW + w) * F4 + f4;
    float4 v = *p;
    v.x *= inv; v.y *= inv; v.z *= inv; v.w *= inv;
    *p = v;
}

// ---- sentence mean into slot 0 ----
__global__ void k_sent(const float* __restrict__ partials, float* __restrict__ out) {
    int t = blockIdx.x * 256 + threadIdx.x;
    if (t >= BB * F4) return;
    int f4 = t % F4;
    int b = t / F4;
    const float4* p4 = (const float4*)partials;
    float4 tot = {0.f, 0.f, 0.f, 0.f};
    #pragma unroll
    for (int g = 0; g < 8; g++) f4add(tot, p4[(b * 8 + g) * F4 + f4]);
    const float s = 1.0f / (float)SS;
    tot.x *= s; tot.y *= s; tot.z *= s; tot.w *= s;
    ((float4*)out)[(size_t)b * NW * F4 + f4] = tot;
}

extern "C" void kernel_launch(void* const* d_in, const int* in_sizes, int n_in,
                              void* d_out, int out_size, void* d_ws, size_t ws_size,
                              hipStream_t stream) {
    const float* hs  = (const float*)d_in[0];   // (L,B,S,F) f32
    const float* lw  = (const float*)d_in[1];   // (L,)
    const float* gm  = (const float*)d_in[2];   // (1,)
    const int*   wid = (const int*)d_in[3];     // (B,S) int32, sorted per row
    float* out = (float*)d_out;                 // (B, 257, F) f32

    int*   counts   = (int*)d_ws;                                   // BB*NW ints
    float* partials = (float*)((char*)d_ws + 33024);                // BB*8*FF floats

    hipMemsetAsync(d_out, 0, (size_t)out_size * sizeof(float), stream);
    k_counts<<<BB, 512, 0, stream>>>(wid, counts);
    k_main<<<BB * 24, 256, 0, stream>>>(hs, lw, gm, wid, out, partials);
    int nm = BB * NW * F4;
    k_means<<<(nm + 255) / 256, 256, 0, stream>>>(out, counts);
    k_sent<<<(BB * F4 + 255) / 256, 256, 0, stream>>>(partials, out);
}